// Round 2
// baseline (424.154 us; speedup 1.0000x reference)
//
#include <hip/hip_runtime.h>
#include <hip/hip_cooperative_groups.h>
#include <math.h>

#define B_ 2
#define S_ 8
#define N_ 150
#define H_ 128
#define F_ 40
#define EF_ 82
#define NP_ 160            // N padded to 10 j-tiles of 16
#define MPQ 136            // mbuf row pitch in bf16 elems (128 + 8 pad)
#define NPAIR 75           // N_/2 node-pairs
#define GRID2 1200         // B*S*NPAIR

namespace cg = cooperative_groups;

typedef __attribute__((ext_vector_type(8))) short short8;
typedef __attribute__((ext_vector_type(4))) float float4v;

__device__ __forceinline__ float silu_f(float v) {
    return v * __builtin_amdgcn_rcpf(1.0f + __expf(-v));
}

// fp32 -> bf16 bits, round-to-nearest-even (must stay identical across rounds)
__device__ __forceinline__ unsigned short f2bf(float f) {
    unsigned u = __builtin_bit_cast(unsigned, f);
    return (unsigned short)((u + 0x7fffu + ((u >> 16) & 1u)) >> 16);
}

// ---------------- prelude: pack_we2 + restore_x + node0 (blockIdx-role-split) ----
__device__ void prelude_dev(const float* __restrict__ W_e2,
                            const float* __restrict__ tW_e2,
                            unsigned short* __restrict__ we2t,
                            const float* __restrict__ x,
                            const float* __restrict__ R,
                            float* __restrict__ xa,
                            float* __restrict__ x0,
                            const int* __restrict__ pep,
                            const int* __restrict__ labels,
                            const int* __restrict__ aapos,
                            const float* __restrict__ We1,
                            const float* __restrict__ be1,
                            const float* __restrict__ tp,
                            const float* __restrict__ wt,
                            const float* __restrict__ wbt,
                            float* __restrict__ h0,
                            float* __restrict__ Af,
                            float* __restrict__ Bf)
{
    int bid = blockIdx.x;
    int tid = threadIdx.x;
    if (bid < 192) {
        // ---- pack We2 -> bf16 transposed [c][k], 3 layers ----
        int e = bid * 256 + tid;                 // 0..49151
        int l = e >> 14, idx = e & 16383;
        int k = idx >> 7, c = idx & 127;
        const float* src = (l == 0) ? W_e2 : (l == 1) ? (W_e2 + H_ * H_) : tW_e2;
        we2t[l * 16384 + c * H_ + k] = f2bf(src[idx]);
    } else if (bid < 221) {
        // ---- restore absolute coords ----
        int idx = (bid - 192) * 256 + tid;
        if (idx < B_ * S_ * N_ * 3) {
            int d = idx % 3;
            int i = (idx / 3) % N_;
            int bs = idx / (3 * N_);
            int b = bs / S_;
            const float* xrow = x + bs * N_ * 3 + d;
            const float* Rrow = R + (b * N_ + i) * N_;
            float acc = 0.0f;
            for (int j = 0; j < N_; j++) acc += xrow[j * 3] * Rrow[j];
            xa[idx] = acc;
            x0[idx] = acc;
        }
    } else if (bid < 371) {
        // ---- node0: one-hot h0 + Af/Bf via 3-row gather (2 (b,i) per block) ----
        int rel = bid - 221;                     // 0..149
        int bi = rel * 2 + (tid >> 7);           // 0..299
        int b = bi / N_, i = bi % N_;
        int c = tid & 127;
        int al = labels[bi];
        int ap = aapos[bi];                      // 1..15
        int aa = pep[b * 15 + ap - 1];
        int r0 = al, r1 = 5 + aa, r2 = 25 + ap - 1;
        float fa = We1[r0 * H_ + c] + We1[r1 * H_ + c] + We1[r2 * H_ + c]
                 + be1[c] + tp[b] * wt[c] + wbt[c];
        float fb = We1[(F_ + r0) * H_ + c] + We1[(F_ + r1) * H_ + c] + We1[(F_ + r2) * H_ + c];
        float hv = 0.0f;
        if (c < F_) hv = (c == r0 || c == r1 || c == r2) ? 1.0f : 0.0f;
        for (int s = 0; s < S_; s++) {
            int n = (b * S_ + s) * N_ + i;
            Af[n * H_ + c] = fa;
            Bf[n * H_ + c] = fb;
            if (c < F_) h0[n * F_ + c] = hv;
        }
    }
}

// ---------------- edge+node phase: block per (bs, node-PAIR) ----------------
// Two nodes (i0,i1) share: xj staging loads, Bfeat row loads, We2 b-frags,
// and the per-iteration barrier. Per-node math is bit-identical to the
// verified 1-node kernel.
__device__ void edge2_dev(
    const float* __restrict__ x_in,    // [BS*N,3]
    const float* __restrict__ Afeat,   // [BS*N,128]
    const float* __restrict__ Bfeat,   // [BS*N,128]
    const float* __restrict__ We1,     // [82,128] rows 80/81
    const unsigned short* __restrict__ we2p,  // [128c][128k] bf16
    const float* __restrict__ be2,
    const float* __restrict__ Wc,
    const float* __restrict__ bcp,
    const float* __restrict__ bond,
    const float* __restrict__ emask,
    const float* __restrict__ h_in,    // node tail
    const float* __restrict__ Wh,      // [168,40]
    const float* __restrict__ bh,      // [40]
    const float* __restrict__ We1n,    // next layer [82,128]
    const float* __restrict__ be1n,
    const float* __restrict__ tp,
    const float* __restrict__ wtn,
    const float* __restrict__ wbtn,
    int has_t,
    const float* __restrict__ x0v,     // final mode only
    const float* __restrict__ amask,   // final mode only
    int final_mode,
    float* __restrict__ x_out,
    float* __restrict__ h_out,
    float* __restrict__ Af_out,
    float* __restrict__ Bf_out)
{
    __shared__ __align__(16) short mbuf[2][2][16 * MPQ];  // [buf][i][row*pitch] 17.4KB
    __shared__ float4 diffE[2][NP_];                      // per-i: d0,d1,d2,em
    __shared__ float2 dbL[2][NP_];                        // per-i: dist, bond
    __shared__ float DsumL[2][3];
    __shared__ float wpart[2][4][3];
    __shared__ float catL[2][F_ + H_];
    __shared__ float partL[2][120];
    __shared__ float hnewL[2][F_];

    int blk = blockIdx.x;
    int bs = blk / NPAIR;
    int pr = blk % NPAIR;
    int i0 = pr * 2, i1 = i0 + 1;
    int b = bs / S_;
    int tid = threadIdx.x;
    int nodeA = bs * N_ + i0, nodeB = nodeA + 1;
    int lane = tid & 63, w = tid >> 6;
    int qd = lane >> 4, l15 = lane & 15;
    int rowLoc = tid >> 4, c0 = (tid & 15) * 8;

    float xiA0 = x_in[nodeA * 3 + 0];
    float xiA1 = x_in[nodeA * 3 + 1];
    float xiA2 = x_in[nodeA * 3 + 2];
    float xiB0 = x_in[nodeB * 3 + 0];
    float xiB1 = x_in[nodeB * 3 + 1];
    float xiB2 = x_in[nodeB * 3 + 2];

    // ---- stage per-j scalars for BOTH i (xj shared) ----
    if (tid < NP_) {
        int j = tid;
        if (j < N_) {
            int nj = bs * N_ + j;
            float xj0 = x_in[nj * 3 + 0];
            float xj1 = x_in[nj * 3 + 1];
            float xj2 = x_in[nj * 3 + 2];
            int eA = (b * N_ + i0) * N_ + j;
            int eB = eA + N_;
            float bndA = bond[eA], bndB = bond[eB];
            float emA = (j == i0) ? 0.0f : emask[eA];
            float emB = (j == i1) ? 0.0f : emask[eB];
            float dA0 = xiA0 - xj0, dA1 = xiA1 - xj1, dA2 = xiA2 - xj2;
            float dB0 = xiB0 - xj0, dB1 = xiB1 - xj1, dB2 = xiB2 - xj2;
            diffE[0][j] = make_float4(dA0, dA1, dA2, emA);
            diffE[1][j] = make_float4(dB0, dB1, dB2, emB);
            dbL[0][j] = make_float2(sqrtf(dA0*dA0 + dA1*dA1 + dA2*dA2 + 1e-12f), bndA);
            dbL[1][j] = make_float2(sqrtf(dB0*dB0 + dB1*dB1 + dB2*dB2 + 1e-12f), bndB);
        } else {
            diffE[0][j] = make_float4(0.f, 0.f, 0.f, 0.f);
            diffE[1][j] = make_float4(0.f, 0.f, 0.f, 0.f);
            dbL[0][j] = make_float2(0.f, 0.f);
            dbL[1][j] = make_float2(0.f, 0.f);
        }
    }

    // ---- hoisted m-compute constants: this thread's 8 channels ----
    float afrA[8], afrB[8], w80r[8], w81r[8];
    {
        float4 t0 = *(const float4*)&Afeat[nodeA * H_ + c0];
        float4 t1 = *(const float4*)&Afeat[nodeA * H_ + c0 + 4];
        afrA[0]=t0.x; afrA[1]=t0.y; afrA[2]=t0.z; afrA[3]=t0.w;
        afrA[4]=t1.x; afrA[5]=t1.y; afrA[6]=t1.z; afrA[7]=t1.w;
        t0 = *(const float4*)&Afeat[nodeB * H_ + c0];
        t1 = *(const float4*)&Afeat[nodeB * H_ + c0 + 4];
        afrB[0]=t0.x; afrB[1]=t0.y; afrB[2]=t0.z; afrB[3]=t0.w;
        afrB[4]=t1.x; afrB[5]=t1.y; afrB[6]=t1.z; afrB[7]=t1.w;
        t0 = *(const float4*)&We1[80 * H_ + c0];
        t1 = *(const float4*)&We1[80 * H_ + c0 + 4];
        w80r[0]=t0.x; w80r[1]=t0.y; w80r[2]=t0.z; w80r[3]=t0.w;
        w80r[4]=t1.x; w80r[5]=t1.y; w80r[6]=t1.z; w80r[7]=t1.w;
        t0 = *(const float4*)&We1[81 * H_ + c0];
        t1 = *(const float4*)&We1[81 * H_ + c0 + 4];
        w81r[0]=t0.x; w81r[1]=t0.y; w81r[2]=t0.z; w81r[3]=t0.w;
        w81r[4]=t1.x; w81r[5]=t1.y; w81r[6]=t1.z; w81r[7]=t1.w;
    }

    // ---- epilogue constants + We2 b-frags (shared across both i) ----
    int ctb = w * 2;
    float b2r0 = be2[ctb * 16 + l15],  b2r1 = be2[ctb * 16 + 16 + l15];
    float wc0  = Wc[ctb * 16 + l15],   wc1  = Wc[ctb * 16 + 16 + l15];
    const unsigned short* bb0 = we2p + (ctb * 16 + l15) * H_ + qd * 8;
    const unsigned short* bb1 = bb0 + 16 * H_;
    short8 bf00 = *(const short8*)(bb0 +  0);
    short8 bf01 = *(const short8*)(bb0 + 32);
    short8 bf02 = *(const short8*)(bb0 + 64);
    short8 bf03 = *(const short8*)(bb0 + 96);
    short8 bf10 = *(const short8*)(bb1 +  0);
    short8 bf11 = *(const short8*)(bb1 + 32);
    short8 bf12 = *(const short8*)(bb1 + 64);
    short8 bf13 = *(const short8*)(bb1 + 96);

    __syncthreads();

    // ---- Dsum per i: wave 0 -> i0, wave 1 -> i1 ----
    if (w < 2) {
        float p0 = 0, p1 = 0, p2 = 0;
        for (int j = lane; j < NP_; j += 64) {
            float4 d = diffE[w][j];
            p0 += d.x; p1 += d.y; p2 += d.z;
        }
        for (int s = 1; s < 64; s <<= 1) {
            p0 += __shfl_xor(p0, s, 64);
            p1 += __shfl_xor(p1, s, 64);
            p2 += __shfl_xor(p2, s, 64);
        }
        if (lane == 0) { DsumL[w][0] = p0; DsumL[w][1] = p1; DsumL[w][2] = p2; }
    }

    float agA0 = 0, agA1 = 0, agB0 = 0, agB1 = 0;
    float SA00 = 0, SA01 = 0, SA02 = 0, SA10 = 0, SA11 = 0, SA12 = 0;
    float SB00 = 0, SB01 = 0, SB02 = 0, SB10 = 0, SB11 = 0, SB12 = 0;

    for (int jt = 0; jt < 10; jt++) {
        short* mbA = mbuf[jt & 1][0];
        short* mbB = mbuf[jt & 1][1];
        // ---- m-compute: this thread's row, 8 channels, both i (Bfeat shared) ----
        int jrow = jt * 16 + rowLoc;
        float mvA[8], mvB[8];
        if (jrow < N_) {
            const float* bp = &Bfeat[(bs * N_ + jrow) * H_ + c0];
            float4 b0 = *(const float4*)bp;
            float4 b1 = *(const float4*)(bp + 4);
            float br[8] = {b0.x, b0.y, b0.z, b0.w, b1.x, b1.y, b1.z, b1.w};
            float2 dA = dbL[0][jrow];
            float2 dB = dbL[1][jrow];
#pragma unroll
            for (int u = 0; u < 8; u++) {
                mvA[u] = silu_f(afrA[u] + br[u] + dA.x * w80r[u] + dA.y * w81r[u]);
                mvB[u] = silu_f(afrB[u] + br[u] + dB.x * w80r[u] + dB.y * w81r[u]);
            }
        } else {
#pragma unroll
            for (int u = 0; u < 8; u++) { mvA[u] = 0.0f; mvB[u] = 0.0f; }
        }
        short8 pkA, pkB;
#pragma unroll
        for (int u = 0; u < 8; u++) { pkA[u] = (short)f2bf(mvA[u]); pkB[u] = (short)f2bf(mvB[u]); }
        *(short8*)&mbA[rowLoc * MPQ + c0] = pkA;
        *(short8*)&mbB[rowLoc * MPQ + c0] = pkB;
        __syncthreads();

        // ---- MFMA for both i ----
        const short* arA = &mbA[l15 * MPQ + qd * 8];
        const short* arB = &mbB[l15 * MPQ + qd * 8];
        short8 aA0 = *(const short8*)(arA +  0);
        short8 aA1 = *(const short8*)(arA + 32);
        short8 aA2 = *(const short8*)(arA + 64);
        short8 aA3 = *(const short8*)(arA + 96);
        short8 aB0 = *(const short8*)(arB +  0);
        short8 aB1 = *(const short8*)(arB + 32);
        short8 aB2 = *(const short8*)(arB + 64);
        short8 aB3 = *(const short8*)(arB + 96);
        float4v accA0 = {0, 0, 0, 0}, accA1 = {0, 0, 0, 0};
        float4v accB0 = {0, 0, 0, 0}, accB1 = {0, 0, 0, 0};
        accA0 = __builtin_amdgcn_mfma_f32_16x16x32_bf16(aA0, bf00, accA0, 0, 0, 0);
        accB0 = __builtin_amdgcn_mfma_f32_16x16x32_bf16(aB0, bf00, accB0, 0, 0, 0);
        accA1 = __builtin_amdgcn_mfma_f32_16x16x32_bf16(aA0, bf10, accA1, 0, 0, 0);
        accB1 = __builtin_amdgcn_mfma_f32_16x16x32_bf16(aB0, bf10, accB1, 0, 0, 0);
        accA0 = __builtin_amdgcn_mfma_f32_16x16x32_bf16(aA1, bf01, accA0, 0, 0, 0);
        accB0 = __builtin_amdgcn_mfma_f32_16x16x32_bf16(aB1, bf01, accB0, 0, 0, 0);
        accA1 = __builtin_amdgcn_mfma_f32_16x16x32_bf16(aA1, bf11, accA1, 0, 0, 0);
        accB1 = __builtin_amdgcn_mfma_f32_16x16x32_bf16(aB1, bf11, accB1, 0, 0, 0);
        accA0 = __builtin_amdgcn_mfma_f32_16x16x32_bf16(aA2, bf02, accA0, 0, 0, 0);
        accB0 = __builtin_amdgcn_mfma_f32_16x16x32_bf16(aB2, bf02, accB0, 0, 0, 0);
        accA1 = __builtin_amdgcn_mfma_f32_16x16x32_bf16(aA2, bf12, accA1, 0, 0, 0);
        accB1 = __builtin_amdgcn_mfma_f32_16x16x32_bf16(aB2, bf12, accB1, 0, 0, 0);
        accA0 = __builtin_amdgcn_mfma_f32_16x16x32_bf16(aA3, bf03, accA0, 0, 0, 0);
        accB0 = __builtin_amdgcn_mfma_f32_16x16x32_bf16(aB3, bf03, accB0, 0, 0, 0);
        accA1 = __builtin_amdgcn_mfma_f32_16x16x32_bf16(aA3, bf13, accA1, 0, 0, 0);
        accB1 = __builtin_amdgcn_mfma_f32_16x16x32_bf16(aB3, bf13, accB1, 0, 0, 0);

        // ---- epilogue: silu, mask, reduce over rows (both i) ----
#pragma unroll
        for (int r = 0; r < 4; r++) {
            int j = jt * 16 + qd * 4 + r;
            float4 deA = diffE[0][j];
            float4 deB = diffE[1][j];
            float mA0 = silu_f(accA0[r] + b2r0) * deA.w;
            float mA1 = silu_f(accA1[r] + b2r1) * deA.w;
            float mB0 = silu_f(accB0[r] + b2r0) * deB.w;
            float mB1 = silu_f(accB1[r] + b2r1) * deB.w;
            agA0 += mA0; agA1 += mA1; agB0 += mB0; agB1 += mB1;
            SA00 += deA.x * mA0; SA01 += deA.y * mA0; SA02 += deA.z * mA0;
            SA10 += deA.x * mA1; SA11 += deA.y * mA1; SA12 += deA.z * mA1;
            SB00 += deB.x * mB0; SB01 += deB.y * mB0; SB02 += deB.z * mB0;
            SB10 += deB.x * mB1; SB11 += deB.y * mB1; SB12 += deB.z * mB1;
        }
    }

    // ---- cross-quad reduction ----
#define QR_(v) { v += __shfl_xor(v, 16, 64); v += __shfl_xor(v, 32, 64); }
    QR_(agA0) QR_(agA1) QR_(agB0) QR_(agB1)
    QR_(SA00) QR_(SA01) QR_(SA02) QR_(SA10) QR_(SA11) QR_(SA12)
    QR_(SB00) QR_(SB01) QR_(SB02) QR_(SB10) QR_(SB11) QR_(SB12)
#undef QR_

    // agg -> LDS for fused node tail
    if (!final_mode) {
        if (qd == 0) {
            catL[0][F_ + ctb * 16 + l15]      = agA0;
            catL[0][F_ + ctb * 16 + 16 + l15] = agA1;
            catL[1][F_ + ctb * 16 + l15]      = agB0;
            catL[1][F_ + ctb * 16 + 16 + l15] = agB1;
        }
        if (tid < F_) catL[0][tid] = h_in[nodeA * F_ + tid];
        else if (tid >= 128 && tid < 128 + F_) catL[1][tid - 128] = h_in[nodeB * F_ + (tid - 128)];
    }

    // deferred cw for both i
    float pA0 = wc0 * SA00 + wc1 * SA10;
    float pA1 = wc0 * SA01 + wc1 * SA11;
    float pA2 = wc0 * SA02 + wc1 * SA12;
    float pB0 = wc0 * SB00 + wc1 * SB10;
    float pB1 = wc0 * SB01 + wc1 * SB11;
    float pB2 = wc0 * SB02 + wc1 * SB12;
    for (int s = 1; s < 16; s <<= 1) {
        pA0 += __shfl_xor(pA0, s, 64);
        pA1 += __shfl_xor(pA1, s, 64);
        pA2 += __shfl_xor(pA2, s, 64);
        pB0 += __shfl_xor(pB0, s, 64);
        pB1 += __shfl_xor(pB1, s, 64);
        pB2 += __shfl_xor(pB2, s, 64);
    }
    if (lane == 0) {
        wpart[0][w][0] = pA0; wpart[0][w][1] = pA1; wpart[0][w][2] = pA2;
        wpart[1][w][0] = pB0; wpart[1][w][1] = pB1; wpart[1][w][2] = pB2;
    }
    __syncthreads();
    if (tid < 3) {
        float tot = wpart[0][0][tid] + wpart[0][1][tid] + wpart[0][2][tid] + wpart[0][3][tid]
                  + bcp[0] * DsumL[0][tid];
        float xn = x_in[nodeA * 3 + tid] + tot * (1.0f / (float)(N_ - 1));
        if (final_mode)
            x_out[nodeA * 3 + tid] = (xn - x0v[nodeA * 3 + tid]) * amask[b * N_ + i0];
        else
            x_out[nodeA * 3 + tid] = xn;
    } else if (tid >= 64 && tid < 67) {
        int d = tid - 64;
        float tot = wpart[1][0][d] + wpart[1][1][d] + wpart[1][2][d] + wpart[1][3][d]
                  + bcp[0] * DsumL[1][d];
        float xn = x_in[nodeB * 3 + d] + tot * (1.0f / (float)(N_ - 1));
        if (final_mode)
            x_out[nodeB * 3 + d] = (xn - x0v[nodeB * 3 + d]) * amask[b * N_ + i1];
        else
            x_out[nodeB * 3 + d] = xn;
    }

    if (final_mode) return;

    // ---- fused node layer, both nodes in parallel (half = tid>>7) ----
    int half = tid >> 7;
    int lt = tid & 127;
    int nodeT = half ? nodeB : nodeA;
    if (lt < 120) {
        int f = lt % 40, ks = lt / 40;   // 3-way k-split of 168 = 3*56
        float p = 0.0f;
        int k0 = ks * 56;
#pragma unroll 8
        for (int k = k0; k < k0 + 56; k++) p += catL[half][k] * Wh[k * F_ + f];
        partL[half][lt] = p;
    }
    __syncthreads();
    if (lt < F_) {
        float hv = silu_f(partL[half][lt] + partL[half][40 + lt] + partL[half][80 + lt] + bh[lt]);
        hnewL[half][lt] = hv;
        h_out[nodeT * F_ + lt] = hv;
    }
    __syncthreads();
    {
        float fa = be1n[lt] + (has_t ? tp[b] * wtn[lt] + wbtn[lt] : 0.0f);
        float fb = 0.0f;
#pragma unroll 8
        for (int k = 0; k < F_; k++) {
            float hv = hnewL[half][k];
            fa += hv * We1n[k * H_ + lt];
            fb += hv * We1n[(F_ + k) * H_ + lt];
        }
        Af_out[nodeT * H_ + lt] = fa;
        Bf_out[nodeT * H_ + lt] = fb;
    }
}

// ---------------- fallback wrappers (non-cooperative path) ----------------
__global__ void prelude_kernel(const float* W_e2, const float* tW_e2,
                               unsigned short* we2t,
                               const float* x, const float* R,
                               float* xa, float* x0,
                               const int* pep, const int* labels, const int* aapos,
                               const float* We1, const float* be1,
                               const float* tp, const float* wt, const float* wbt,
                               float* h0, float* Af, float* Bf) {
    prelude_dev(W_e2, tW_e2, we2t, x, R, xa, x0, pep, labels, aapos,
                We1, be1, tp, wt, wbt, h0, Af, Bf);
}

__global__ __launch_bounds__(256, 5) void edge2_kernel(
    const float* x_in, const float* Afeat, const float* Bfeat,
    const float* We1, const unsigned short* we2p, const float* be2,
    const float* Wc, const float* bcp, const float* bond, const float* emask,
    const float* h_in, const float* Wh, const float* bh,
    const float* We1n, const float* be1n,
    const float* tp, const float* wtn, const float* wbtn, int has_t,
    const float* x0v, const float* amask, int final_mode,
    float* x_out, float* h_out, float* Af_out, float* Bf_out) {
    edge2_dev(x_in, Afeat, Bfeat, We1, we2p, be2, Wc, bcp, bond, emask,
              h_in, Wh, bh, We1n, be1n, tp, wtn, wbtn, has_t,
              x0v, amask, final_mode, x_out, h_out, Af_out, Bf_out);
}

// ---------------- single cooperative mega kernel ----------------
__global__ __launch_bounds__(256, 5) void mega_kernel(
    const float* W_e2, const float* tW_e2, unsigned short* we2t,
    const float* x, const float* R, float* xA, float* x0,
    const int* pep, const int* labels, const int* aapos,
    const float* W_e1, const float* b_e1,
    const float* tvec, const float* w_t, const float* w_b_t,
    float* hA, float* Af1, float* Bf1,
    const float* b_e2, const float* W_c, const float* b_c,
    const float* W_h, const float* b_h,
    const float* tW_e1, const float* tb_e1, const float* tb_e2,
    const float* tW_c, const float* tb_c,
    const float* bond, const float* em, const float* amask,
    float* xB, float* hB, float* Af2, float* Bf2, float* out)
{
    cg::grid_group grid = cg::this_grid();

    prelude_dev(W_e2, tW_e2, we2t, x, R, xA, x0, pep, labels, aapos,
                W_e1, b_e1, tvec, w_t, w_b_t, hA, Af1, Bf1);
    grid.sync();

    // layer 0 (edge + fused node -> layer-1 feats)
    edge2_dev(xA, Af1, Bf1, W_e1, we2t, b_e2, W_c, b_c, bond, em,
              hA, W_h, b_h, W_e1 + EF_ * H_, b_e1 + H_,
              tvec, w_t + H_, w_b_t + H_, 1,
              nullptr, nullptr, 0, xB, hB, Af2, Bf2);
    grid.sync();

    // layer 1 (edge + fused node -> t-layer feats)
    edge2_dev(xB, Af2, Bf2, W_e1 + EF_ * H_, we2t + 16384, b_e2 + H_,
              W_c + H_, b_c + 1, bond, em,
              hB, W_h + (F_ + H_) * F_, b_h + F_, tW_e1, tb_e1,
              nullptr, nullptr, nullptr, 0,
              nullptr, nullptr, 0, xA, hA, Af1, Bf1);
    grid.sync();

    // t layer: final output
    edge2_dev(xA, Af1, Bf1, tW_e1, we2t + 32768, tb_e2, tW_c, tb_c, bond, em,
              nullptr, nullptr, nullptr, nullptr, nullptr,
              nullptr, nullptr, nullptr, 0,
              x0, amask, 1, out, nullptr, nullptr, nullptr);
}

extern "C" void kernel_launch(void* const* d_in, const int* in_sizes, int n_in,
                              void* d_out, int out_size, void* d_ws, size_t ws_size,
                              hipStream_t stream) {
    const float* t     = (const float*)d_in[0];
    const float* x     = (const float*)d_in[1];
    const int*   pep   = (const int*)d_in[2];
    const int*   labels= (const int*)d_in[3];
    const int*   aapos = (const int*)d_in[4];
    const float* bond  = (const float*)d_in[5];
    const float* em    = (const float*)d_in[6];
    const float* amask = (const float*)d_in[7];
    const float* R     = (const float*)d_in[8];
    const float* W_e1  = (const float*)d_in[9];
    const float* b_e1  = (const float*)d_in[10];
    const float* W_e2  = (const float*)d_in[11];
    const float* b_e2  = (const float*)d_in[12];
    const float* W_c   = (const float*)d_in[13];
    const float* b_c   = (const float*)d_in[14];
    const float* W_h   = (const float*)d_in[15];
    const float* b_h   = (const float*)d_in[16];
    const float* w_t   = (const float*)d_in[17];
    const float* w_b_t = (const float*)d_in[18];
    const float* tW_e1 = (const float*)d_in[19];
    const float* tb_e1 = (const float*)d_in[20];
    const float* tW_e2 = (const float*)d_in[21];
    const float* tb_e2 = (const float*)d_in[22];
    const float* tW_c  = (const float*)d_in[23];
    const float* tb_c  = (const float*)d_in[24];
    float* out = (float*)d_out;

    float* ws = (float*)d_ws;
    unsigned short* we2t = (unsigned short*)ws;   // 49152 shorts
    float* x0  = ws + 24576;         // 7200
    float* xA  = x0 + 7200;          // 7200
    float* xB  = xA + 7200;          // 7200
    float* hA  = xB + 7200;          // 96000
    float* hB  = hA + 96000;         // 96000
    float* Af1 = hB + 96000;         // 307200
    float* Bf1 = Af1 + 307200;       // 307200
    float* Af2 = Bf1 + 307200;       // 307200
    float* Bf2 = Af2 + 307200;       // 307200

    // decide coop vs fallback once (host-only queries; capture-safe)
    static int coop_state = -1;
    if (coop_state < 0) {
        int nb = 0;
        hipError_t e1 = hipOccupancyMaxActiveBlocksPerMultiprocessor(
            &nb, reinterpret_cast<const void*>(mega_kernel), 256, 0);
        hipDeviceProp_t prop;
        int dev = 0;
        hipGetDevice(&dev);
        hipError_t e2 = hipGetDeviceProperties(&prop, dev);
        coop_state = (e1 == hipSuccess && e2 == hipSuccess &&
                      prop.cooperativeLaunch &&
                      (long)nb * prop.multiProcessorCount >= GRID2) ? 1 : 0;
    }

    bool launched = false;
    if (coop_state == 1) {
        void* args[] = {
            (void*)&W_e2, (void*)&tW_e2, (void*)&we2t,
            (void*)&x, (void*)&R, (void*)&xA, (void*)&x0,
            (void*)&pep, (void*)&labels, (void*)&aapos,
            (void*)&W_e1, (void*)&b_e1,
            (void*)&t, (void*)&w_t, (void*)&w_b_t,
            (void*)&hA, (void*)&Af1, (void*)&Bf1,
            (void*)&b_e2, (void*)&W_c, (void*)&b_c,
            (void*)&W_h, (void*)&b_h,
            (void*)&tW_e1, (void*)&tb_e1, (void*)&tb_e2,
            (void*)&tW_c, (void*)&tb_c,
            (void*)&bond, (void*)&em, (void*)&amask,
            (void*)&xB, (void*)&hB, (void*)&Af2, (void*)&Bf2, (void*)&out
        };
        hipError_t e = hipLaunchCooperativeKernel(
            reinterpret_cast<const void*>(mega_kernel),
            dim3(GRID2), dim3(256), args, 0, stream);
        launched = (e == hipSuccess);
        if (!launched) coop_state = 0;
    }

    if (!launched) {
        prelude_kernel<<<371, 256, 0, stream>>>(W_e2, tW_e2, we2t, x, R, xA, x0,
                                                pep, labels, aapos, W_e1, b_e1,
                                                t, w_t, w_b_t, hA, Af1, Bf1);
        edge2_kernel<<<GRID2, 256, 0, stream>>>(
            xA, Af1, Bf1, W_e1, we2t, b_e2, W_c, b_c, bond, em,
            hA, W_h, b_h, W_e1 + EF_ * H_, b_e1 + H_, t, w_t + H_, w_b_t + H_, 1,
            nullptr, nullptr, 0, xB, hB, Af2, Bf2);
        edge2_kernel<<<GRID2, 256, 0, stream>>>(
            xB, Af2, Bf2, W_e1 + EF_ * H_, we2t + 16384, b_e2 + H_, W_c + H_, b_c + 1,
            bond, em, hB, W_h + (F_ + H_) * F_, b_h + F_, tW_e1, tb_e1,
            nullptr, nullptr, nullptr, 0,
            nullptr, nullptr, 0, xA, hA, Af1, Bf1);
        edge2_kernel<<<GRID2, 256, 0, stream>>>(
            xA, Af1, Bf1, tW_e1, we2t + 32768, tb_e2, tW_c, tb_c, bond, em,
            nullptr, nullptr, nullptr, nullptr, nullptr, nullptr, nullptr, nullptr, 0,
            x0, amask, 1, out, nullptr, nullptr, nullptr);
    }
}

// Round 3
// 292.987 us; speedup vs baseline: 1.4477x; 1.4477x over previous
//
#include <hip/hip_runtime.h>
#include <math.h>

#define B_ 2
#define S_ 8
#define N_ 150
#define H_ 128
#define F_ 40
#define EF_ 82
#define NP_ 160            // N padded to 10 j-tiles of 16
#define MPQ 136            // mbuf row pitch in bf16 elems (128 + 8 pad)
#define NPAIR 75           // N_/2 node-pairs
#define GRID2 1200         // B*S*NPAIR

typedef __attribute__((ext_vector_type(8))) short short8;
typedef __attribute__((ext_vector_type(4))) float float4v;

__device__ __forceinline__ float silu_f(float v) {
    return v * __builtin_amdgcn_rcpf(1.0f + __expf(-v));
}

// fp32 -> bf16 bits, round-to-nearest-even (must stay identical across rounds)
__device__ __forceinline__ unsigned short f2bf(float f) {
    unsigned u = __builtin_bit_cast(unsigned, f);
    return (unsigned short)((u + 0x7fffu + ((u >> 16) & 1u)) >> 16);
}

// ---------------- prelude: pack_we2 + restore_x + node0 in ONE dispatch ----------
__global__ void prelude_kernel(const float* __restrict__ W_e2,
                               const float* __restrict__ tW_e2,
                               unsigned short* __restrict__ we2t,
                               const float* __restrict__ x,
                               const float* __restrict__ R,
                               float* __restrict__ xa,
                               float* __restrict__ x0,
                               const int* __restrict__ pep,
                               const int* __restrict__ labels,
                               const int* __restrict__ aapos,
                               const float* __restrict__ We1,
                               const float* __restrict__ be1,
                               const float* __restrict__ tp,
                               const float* __restrict__ wt,
                               const float* __restrict__ wbt,
                               float* __restrict__ h0,
                               float* __restrict__ Af,
                               float* __restrict__ Bf) {
    int bid = blockIdx.x;
    int tid = threadIdx.x;
    if (bid < 192) {
        // ---- pack We2 -> bf16 transposed [c][k], 3 layers ----
        int e = bid * 256 + tid;                 // 0..49151
        int l = e >> 14, idx = e & 16383;
        int k = idx >> 7, c = idx & 127;
        const float* src = (l == 0) ? W_e2 : (l == 1) ? (W_e2 + H_ * H_) : tW_e2;
        we2t[l * 16384 + c * H_ + k] = f2bf(src[idx]);
    } else if (bid < 221) {
        // ---- restore absolute coords ----
        int idx = (bid - 192) * 256 + tid;
        if (idx < B_ * S_ * N_ * 3) {
            int d = idx % 3;
            int i = (idx / 3) % N_;
            int bs = idx / (3 * N_);
            int b = bs / S_;
            const float* xrow = x + bs * N_ * 3 + d;
            const float* Rrow = R + (b * N_ + i) * N_;
            float acc = 0.0f;
            for (int j = 0; j < N_; j++) acc += xrow[j * 3] * Rrow[j];
            xa[idx] = acc;
            x0[idx] = acc;
        }
    } else {
        // ---- node0: one-hot h0 + Af/Bf via 3-row gather (2 (b,i) per block) ----
        int rel = bid - 221;                     // 0..149
        int bi = rel * 2 + (tid >> 7);           // 0..299
        int b = bi / N_, i = bi % N_;
        int c = tid & 127;
        int al = labels[bi];
        int ap = aapos[bi];                      // 1..15
        int aa = pep[b * 15 + ap - 1];
        int r0 = al, r1 = 5 + aa, r2 = 25 + ap - 1;
        float fa = We1[r0 * H_ + c] + We1[r1 * H_ + c] + We1[r2 * H_ + c]
                 + be1[c] + tp[b] * wt[c] + wbt[c];
        float fb = We1[(F_ + r0) * H_ + c] + We1[(F_ + r1) * H_ + c] + We1[(F_ + r2) * H_ + c];
        float hv = 0.0f;
        if (c < F_) hv = (c == r0 || c == r1 || c == r2) ? 1.0f : 0.0f;
        for (int s = 0; s < S_; s++) {
            int n = (b * S_ + s) * N_ + i;
            Af[n * H_ + c] = fa;
            Bf[n * H_ + c] = fb;
            if (c < F_) h0[n * F_ + c] = hv;
        }
    }
}

// ---------------- edge+node: block per (bs, node-PAIR) ----------------
// Two nodes (i0,i1) share: xj staging loads, Bfeat row loads, We2 b-frags,
// and the per-iteration barrier. Per-node math is bit-identical to the
// verified 1-node kernel. launch_bounds(256,4): 128-VGPR budget, no spills;
// LDS (28.2 KB) caps residency at 5 blocks/CU anyway.
__global__ __launch_bounds__(256, 4) void edge2_kernel(
    const float* __restrict__ x_in,    // [BS*N,3]
    const float* __restrict__ Afeat,   // [BS*N,128]
    const float* __restrict__ Bfeat,   // [BS*N,128]
    const float* __restrict__ We1,     // [82,128] rows 80/81
    const unsigned short* __restrict__ we2p,  // [128c][128k] bf16
    const float* __restrict__ be2,
    const float* __restrict__ Wc,
    const float* __restrict__ bcp,
    const float* __restrict__ bond,
    const float* __restrict__ emask,
    const float* __restrict__ h_in,    // node tail
    const float* __restrict__ Wh,      // [168,40]
    const float* __restrict__ bh,      // [40]
    const float* __restrict__ We1n,    // next layer [82,128]
    const float* __restrict__ be1n,
    const float* __restrict__ tp,
    const float* __restrict__ wtn,
    const float* __restrict__ wbtn,
    int has_t,
    const float* __restrict__ x0v,     // final mode only
    const float* __restrict__ amask,   // final mode only
    int final_mode,
    float* __restrict__ x_out,
    float* __restrict__ h_out,
    float* __restrict__ Af_out,
    float* __restrict__ Bf_out)
{
    __shared__ __align__(16) short mbuf[2][2][16 * MPQ];  // [buf][i][row*pitch] 17.4KB
    __shared__ float4 diffE[2][NP_];                      // per-i: d0,d1,d2,em
    __shared__ float2 dbL[2][NP_];                        // per-i: dist, bond
    __shared__ float DsumL[2][3];
    __shared__ float wpart[2][4][3];
    __shared__ float catL[2][F_ + H_];
    __shared__ float partL[2][120];
    __shared__ float hnewL[2][F_];

    int blk = blockIdx.x;
    int bs = blk / NPAIR;
    int pr = blk % NPAIR;
    int i0 = pr * 2, i1 = i0 + 1;
    int b = bs / S_;
    int tid = threadIdx.x;
    int nodeA = bs * N_ + i0, nodeB = nodeA + 1;
    int lane = tid & 63, w = tid >> 6;
    int qd = lane >> 4, l15 = lane & 15;
    int rowLoc = tid >> 4, c0 = (tid & 15) * 8;

    float xiA0 = x_in[nodeA * 3 + 0];
    float xiA1 = x_in[nodeA * 3 + 1];
    float xiA2 = x_in[nodeA * 3 + 2];
    float xiB0 = x_in[nodeB * 3 + 0];
    float xiB1 = x_in[nodeB * 3 + 1];
    float xiB2 = x_in[nodeB * 3 + 2];

    // ---- stage per-j scalars for BOTH i (xj shared) ----
    if (tid < NP_) {
        int j = tid;
        if (j < N_) {
            int nj = bs * N_ + j;
            float xj0 = x_in[nj * 3 + 0];
            float xj1 = x_in[nj * 3 + 1];
            float xj2 = x_in[nj * 3 + 2];
            int eA = (b * N_ + i0) * N_ + j;
            int eB = eA + N_;
            float bndA = bond[eA], bndB = bond[eB];
            float emA = (j == i0) ? 0.0f : emask[eA];
            float emB = (j == i1) ? 0.0f : emask[eB];
            float dA0 = xiA0 - xj0, dA1 = xiA1 - xj1, dA2 = xiA2 - xj2;
            float dB0 = xiB0 - xj0, dB1 = xiB1 - xj1, dB2 = xiB2 - xj2;
            diffE[0][j] = make_float4(dA0, dA1, dA2, emA);
            diffE[1][j] = make_float4(dB0, dB1, dB2, emB);
            dbL[0][j] = make_float2(sqrtf(dA0*dA0 + dA1*dA1 + dA2*dA2 + 1e-12f), bndA);
            dbL[1][j] = make_float2(sqrtf(dB0*dB0 + dB1*dB1 + dB2*dB2 + 1e-12f), bndB);
        } else {
            diffE[0][j] = make_float4(0.f, 0.f, 0.f, 0.f);
            diffE[1][j] = make_float4(0.f, 0.f, 0.f, 0.f);
            dbL[0][j] = make_float2(0.f, 0.f);
            dbL[1][j] = make_float2(0.f, 0.f);
        }
    }

    // ---- hoisted m-compute constants: this thread's 8 channels ----
    float afrA[8], afrB[8], w80r[8], w81r[8];
    {
        float4 t0 = *(const float4*)&Afeat[nodeA * H_ + c0];
        float4 t1 = *(const float4*)&Afeat[nodeA * H_ + c0 + 4];
        afrA[0]=t0.x; afrA[1]=t0.y; afrA[2]=t0.z; afrA[3]=t0.w;
        afrA[4]=t1.x; afrA[5]=t1.y; afrA[6]=t1.z; afrA[7]=t1.w;
        t0 = *(const float4*)&Afeat[nodeB * H_ + c0];
        t1 = *(const float4*)&Afeat[nodeB * H_ + c0 + 4];
        afrB[0]=t0.x; afrB[1]=t0.y; afrB[2]=t0.z; afrB[3]=t0.w;
        afrB[4]=t1.x; afrB[5]=t1.y; afrB[6]=t1.z; afrB[7]=t1.w;
        t0 = *(const float4*)&We1[80 * H_ + c0];
        t1 = *(const float4*)&We1[80 * H_ + c0 + 4];
        w80r[0]=t0.x; w80r[1]=t0.y; w80r[2]=t0.z; w80r[3]=t0.w;
        w80r[4]=t1.x; w80r[5]=t1.y; w80r[6]=t1.z; w80r[7]=t1.w;
        t0 = *(const float4*)&We1[81 * H_ + c0];
        t1 = *(const float4*)&We1[81 * H_ + c0 + 4];
        w81r[0]=t0.x; w81r[1]=t0.y; w81r[2]=t0.z; w81r[3]=t0.w;
        w81r[4]=t1.x; w81r[5]=t1.y; w81r[6]=t1.z; w81r[7]=t1.w;
    }

    // ---- epilogue constants + We2 b-frags (shared across both i) ----
    int ctb = w * 2;
    float b2r0 = be2[ctb * 16 + l15],  b2r1 = be2[ctb * 16 + 16 + l15];
    float wc0  = Wc[ctb * 16 + l15],   wc1  = Wc[ctb * 16 + 16 + l15];
    const unsigned short* bb0 = we2p + (ctb * 16 + l15) * H_ + qd * 8;
    const unsigned short* bb1 = bb0 + 16 * H_;
    short8 bf00 = *(const short8*)(bb0 +  0);
    short8 bf01 = *(const short8*)(bb0 + 32);
    short8 bf02 = *(const short8*)(bb0 + 64);
    short8 bf03 = *(const short8*)(bb0 + 96);
    short8 bf10 = *(const short8*)(bb1 +  0);
    short8 bf11 = *(const short8*)(bb1 + 32);
    short8 bf12 = *(const short8*)(bb1 + 64);
    short8 bf13 = *(const short8*)(bb1 + 96);

    __syncthreads();

    // ---- Dsum per i: wave 0 -> i0, wave 1 -> i1 ----
    if (w < 2) {
        float p0 = 0, p1 = 0, p2 = 0;
        for (int j = lane; j < NP_; j += 64) {
            float4 d = diffE[w][j];
            p0 += d.x; p1 += d.y; p2 += d.z;
        }
        for (int s = 1; s < 64; s <<= 1) {
            p0 += __shfl_xor(p0, s, 64);
            p1 += __shfl_xor(p1, s, 64);
            p2 += __shfl_xor(p2, s, 64);
        }
        if (lane == 0) { DsumL[w][0] = p0; DsumL[w][1] = p1; DsumL[w][2] = p2; }
    }

    float agA0 = 0, agA1 = 0, agB0 = 0, agB1 = 0;
    float SA00 = 0, SA01 = 0, SA02 = 0, SA10 = 0, SA11 = 0, SA12 = 0;
    float SB00 = 0, SB01 = 0, SB02 = 0, SB10 = 0, SB11 = 0, SB12 = 0;

    for (int jt = 0; jt < 10; jt++) {
        short* mbA = mbuf[jt & 1][0];
        short* mbB = mbuf[jt & 1][1];
        // ---- m-compute: this thread's row, 8 channels, both i (Bfeat shared) ----
        int jrow = jt * 16 + rowLoc;
        float mvA[8], mvB[8];
        if (jrow < N_) {
            const float* bp = &Bfeat[(bs * N_ + jrow) * H_ + c0];
            float4 b0 = *(const float4*)bp;
            float4 b1 = *(const float4*)(bp + 4);
            float br[8] = {b0.x, b0.y, b0.z, b0.w, b1.x, b1.y, b1.z, b1.w};
            float2 dA = dbL[0][jrow];
            float2 dB = dbL[1][jrow];
#pragma unroll
            for (int u = 0; u < 8; u++) {
                mvA[u] = silu_f(afrA[u] + br[u] + dA.x * w80r[u] + dA.y * w81r[u]);
                mvB[u] = silu_f(afrB[u] + br[u] + dB.x * w80r[u] + dB.y * w81r[u]);
            }
        } else {
#pragma unroll
            for (int u = 0; u < 8; u++) { mvA[u] = 0.0f; mvB[u] = 0.0f; }
        }
        short8 pkA, pkB;
#pragma unroll
        for (int u = 0; u < 8; u++) { pkA[u] = (short)f2bf(mvA[u]); pkB[u] = (short)f2bf(mvB[u]); }
        *(short8*)&mbA[rowLoc * MPQ + c0] = pkA;
        *(short8*)&mbB[rowLoc * MPQ + c0] = pkB;
        __syncthreads();

        // ---- MFMA for both i ----
        const short* arA = &mbA[l15 * MPQ + qd * 8];
        const short* arB = &mbB[l15 * MPQ + qd * 8];
        short8 aA0 = *(const short8*)(arA +  0);
        short8 aA1 = *(const short8*)(arA + 32);
        short8 aA2 = *(const short8*)(arA + 64);
        short8 aA3 = *(const short8*)(arA + 96);
        short8 aB0 = *(const short8*)(arB +  0);
        short8 aB1 = *(const short8*)(arB + 32);
        short8 aB2 = *(const short8*)(arB + 64);
        short8 aB3 = *(const short8*)(arB + 96);
        float4v accA0 = {0, 0, 0, 0}, accA1 = {0, 0, 0, 0};
        float4v accB0 = {0, 0, 0, 0}, accB1 = {0, 0, 0, 0};
        accA0 = __builtin_amdgcn_mfma_f32_16x16x32_bf16(aA0, bf00, accA0, 0, 0, 0);
        accB0 = __builtin_amdgcn_mfma_f32_16x16x32_bf16(aB0, bf00, accB0, 0, 0, 0);
        accA1 = __builtin_amdgcn_mfma_f32_16x16x32_bf16(aA0, bf10, accA1, 0, 0, 0);
        accB1 = __builtin_amdgcn_mfma_f32_16x16x32_bf16(aB0, bf10, accB1, 0, 0, 0);
        accA0 = __builtin_amdgcn_mfma_f32_16x16x32_bf16(aA1, bf01, accA0, 0, 0, 0);
        accB0 = __builtin_amdgcn_mfma_f32_16x16x32_bf16(aB1, bf01, accB0, 0, 0, 0);
        accA1 = __builtin_amdgcn_mfma_f32_16x16x32_bf16(aA1, bf11, accA1, 0, 0, 0);
        accB1 = __builtin_amdgcn_mfma_f32_16x16x32_bf16(aB1, bf11, accB1, 0, 0, 0);
        accA0 = __builtin_amdgcn_mfma_f32_16x16x32_bf16(aA2, bf02, accA0, 0, 0, 0);
        accB0 = __builtin_amdgcn_mfma_f32_16x16x32_bf16(aB2, bf02, accB0, 0, 0, 0);
        accA1 = __builtin_amdgcn_mfma_f32_16x16x32_bf16(aA2, bf12, accA1, 0, 0, 0);
        accB1 = __builtin_amdgcn_mfma_f32_16x16x32_bf16(aB2, bf12, accB1, 0, 0, 0);
        accA0 = __builtin_amdgcn_mfma_f32_16x16x32_bf16(aA3, bf03, accA0, 0, 0, 0);
        accB0 = __builtin_amdgcn_mfma_f32_16x16x32_bf16(aB3, bf03, accB0, 0, 0, 0);
        accA1 = __builtin_amdgcn_mfma_f32_16x16x32_bf16(aA3, bf13, accA1, 0, 0, 0);
        accB1 = __builtin_amdgcn_mfma_f32_16x16x32_bf16(aB3, bf13, accB1, 0, 0, 0);

        // ---- epilogue: silu, mask, reduce over rows (both i) ----
#pragma unroll
        for (int r = 0; r < 4; r++) {
            int j = jt * 16 + qd * 4 + r;
            float4 deA = diffE[0][j];
            float4 deB = diffE[1][j];
            float mA0 = silu_f(accA0[r] + b2r0) * deA.w;
            float mA1 = silu_f(accA1[r] + b2r1) * deA.w;
            float mB0 = silu_f(accB0[r] + b2r0) * deB.w;
            float mB1 = silu_f(accB1[r] + b2r1) * deB.w;
            agA0 += mA0; agA1 += mA1; agB0 += mB0; agB1 += mB1;
            SA00 += deA.x * mA0; SA01 += deA.y * mA0; SA02 += deA.z * mA0;
            SA10 += deA.x * mA1; SA11 += deA.y * mA1; SA12 += deA.z * mA1;
            SB00 += deB.x * mB0; SB01 += deB.y * mB0; SB02 += deB.z * mB0;
            SB10 += deB.x * mB1; SB11 += deB.y * mB1; SB12 += deB.z * mB1;
        }
    }

    // ---- cross-quad reduction ----
#define QR_(v) { v += __shfl_xor(v, 16, 64); v += __shfl_xor(v, 32, 64); }
    QR_(agA0) QR_(agA1) QR_(agB0) QR_(agB1)
    QR_(SA00) QR_(SA01) QR_(SA02) QR_(SA10) QR_(SA11) QR_(SA12)
    QR_(SB00) QR_(SB01) QR_(SB02) QR_(SB10) QR_(SB11) QR_(SB12)
#undef QR_

    // agg -> LDS for fused node tail
    if (!final_mode) {
        if (qd == 0) {
            catL[0][F_ + ctb * 16 + l15]      = agA0;
            catL[0][F_ + ctb * 16 + 16 + l15] = agA1;
            catL[1][F_ + ctb * 16 + l15]      = agB0;
            catL[1][F_ + ctb * 16 + 16 + l15] = agB1;
        }
        if (tid < F_) catL[0][tid] = h_in[nodeA * F_ + tid];
        else if (tid >= 128 && tid < 128 + F_) catL[1][tid - 128] = h_in[nodeB * F_ + (tid - 128)];
    }

    // deferred cw for both i
    float pA0 = wc0 * SA00 + wc1 * SA10;
    float pA1 = wc0 * SA01 + wc1 * SA11;
    float pA2 = wc0 * SA02 + wc1 * SA12;
    float pB0 = wc0 * SB00 + wc1 * SB10;
    float pB1 = wc0 * SB01 + wc1 * SB11;
    float pB2 = wc0 * SB02 + wc1 * SB12;
    for (int s = 1; s < 16; s <<= 1) {
        pA0 += __shfl_xor(pA0, s, 64);
        pA1 += __shfl_xor(pA1, s, 64);
        pA2 += __shfl_xor(pA2, s, 64);
        pB0 += __shfl_xor(pB0, s, 64);
        pB1 += __shfl_xor(pB1, s, 64);
        pB2 += __shfl_xor(pB2, s, 64);
    }
    if (lane == 0) {
        wpart[0][w][0] = pA0; wpart[0][w][1] = pA1; wpart[0][w][2] = pA2;
        wpart[1][w][0] = pB0; wpart[1][w][1] = pB1; wpart[1][w][2] = pB2;
    }
    __syncthreads();
    if (tid < 3) {
        float tot = wpart[0][0][tid] + wpart[0][1][tid] + wpart[0][2][tid] + wpart[0][3][tid]
                  + bcp[0] * DsumL[0][tid];
        float xn = x_in[nodeA * 3 + tid] + tot * (1.0f / (float)(N_ - 1));
        if (final_mode)
            x_out[nodeA * 3 + tid] = (xn - x0v[nodeA * 3 + tid]) * amask[b * N_ + i0];
        else
            x_out[nodeA * 3 + tid] = xn;
    } else if (tid >= 64 && tid < 67) {
        int d = tid - 64;
        float tot = wpart[1][0][d] + wpart[1][1][d] + wpart[1][2][d] + wpart[1][3][d]
                  + bcp[0] * DsumL[1][d];
        float xn = x_in[nodeB * 3 + d] + tot * (1.0f / (float)(N_ - 1));
        if (final_mode)
            x_out[nodeB * 3 + d] = (xn - x0v[nodeB * 3 + d]) * amask[b * N_ + i1];
        else
            x_out[nodeB * 3 + d] = xn;
    }

    if (final_mode) return;

    // ---- fused node layer, both nodes in parallel (half = tid>>7) ----
    int half = tid >> 7;
    int lt = tid & 127;
    int nodeT = half ? nodeB : nodeA;
    if (lt < 120) {
        int f = lt % 40, ks = lt / 40;   // 3-way k-split of 168 = 3*56
        float p = 0.0f;
        int k0 = ks * 56;
#pragma unroll 8
        for (int k = k0; k < k0 + 56; k++) p += catL[half][k] * Wh[k * F_ + f];
        partL[half][lt] = p;
    }
    __syncthreads();
    if (lt < F_) {
        float hv = silu_f(partL[half][lt] + partL[half][40 + lt] + partL[half][80 + lt] + bh[lt]);
        hnewL[half][lt] = hv;
        h_out[nodeT * F_ + lt] = hv;
    }
    __syncthreads();
    {
        float fa = be1n[lt] + (has_t ? tp[b] * wtn[lt] + wbtn[lt] : 0.0f);
        float fb = 0.0f;
#pragma unroll 8
        for (int k = 0; k < F_; k++) {
            float hv = hnewL[half][k];
            fa += hv * We1n[k * H_ + lt];
            fb += hv * We1n[(F_ + k) * H_ + lt];
        }
        Af_out[nodeT * H_ + lt] = fa;
        Bf_out[nodeT * H_ + lt] = fb;
    }
}

extern "C" void kernel_launch(void* const* d_in, const int* in_sizes, int n_in,
                              void* d_out, int out_size, void* d_ws, size_t ws_size,
                              hipStream_t stream) {
    const float* t     = (const float*)d_in[0];
    const float* x     = (const float*)d_in[1];
    const int*   pep   = (const int*)d_in[2];
    const int*   labels= (const int*)d_in[3];
    const int*   aapos = (const int*)d_in[4];
    const float* bond  = (const float*)d_in[5];
    const float* em    = (const float*)d_in[6];
    const float* amask = (const float*)d_in[7];
    const float* R     = (const float*)d_in[8];
    const float* W_e1  = (const float*)d_in[9];
    const float* b_e1  = (const float*)d_in[10];
    const float* W_e2  = (const float*)d_in[11];
    const float* b_e2  = (const float*)d_in[12];
    const float* W_c   = (const float*)d_in[13];
    const float* b_c   = (const float*)d_in[14];
    const float* W_h   = (const float*)d_in[15];
    const float* b_h   = (const float*)d_in[16];
    const float* w_t   = (const float*)d_in[17];
    const float* w_b_t = (const float*)d_in[18];
    const float* tW_e1 = (const float*)d_in[19];
    const float* tb_e1 = (const float*)d_in[20];
    const float* tW_e2 = (const float*)d_in[21];
    const float* tb_e2 = (const float*)d_in[22];
    const float* tW_c  = (const float*)d_in[23];
    const float* tb_c  = (const float*)d_in[24];
    float* out = (float*)d_out;

    float* ws = (float*)d_ws;
    unsigned short* we2t = (unsigned short*)ws;   // 49152 shorts
    float* x0  = ws + 24576;         // 7200
    float* xA  = x0 + 7200;          // 7200
    float* xB  = xA + 7200;          // 7200
    float* hA  = xB + 7200;          // 96000
    float* hB  = hA + 96000;         // 96000
    float* Af1 = hB + 96000;         // 307200
    float* Bf1 = Af1 + 307200;       // 307200
    float* Af2 = Bf1 + 307200;       // 307200
    float* Bf2 = Af2 + 307200;       // 307200

    prelude_kernel<<<371, 256, 0, stream>>>(W_e2, tW_e2, we2t, x, R, xA, x0,
                                            pep, labels, aapos, W_e1, b_e1,
                                            t, w_t, w_b_t, hA, Af1, Bf1);

    // ---- layer 0 (edge + fused node -> layer-1 feats) ----
    edge2_kernel<<<GRID2, 256, 0, stream>>>(
        xA, Af1, Bf1, W_e1, we2t, b_e2, W_c, b_c, bond, em,
        hA, W_h, b_h, W_e1 + EF_ * H_, b_e1 + H_, t, w_t + H_, w_b_t + H_, 1,
        nullptr, nullptr, 0, xB, hB, Af2, Bf2);

    // ---- layer 1 (edge + fused node -> t-layer feats) ----
    edge2_kernel<<<GRID2, 256, 0, stream>>>(
        xB, Af2, Bf2, W_e1 + EF_ * H_, we2t + 16384, b_e2 + H_, W_c + H_, b_c + 1,
        bond, em, hB, W_h + (F_ + H_) * F_, b_h + F_, tW_e1, tb_e1,
        nullptr, nullptr, nullptr, 0,
        nullptr, nullptr, 0, xA, hA, Af1, Bf1);

    // ---- t layer: fused final output (no node tail) ----
    edge2_kernel<<<GRID2, 256, 0, stream>>>(
        xA, Af1, Bf1, tW_e1, we2t + 32768, tb_e2, tW_c, tb_c, bond, em,
        nullptr, nullptr, nullptr, nullptr, nullptr, nullptr, nullptr, nullptr, 0,
        x0, amask, 1, out, nullptr, nullptr, nullptr);
}